// Round 1
// baseline (117.689 us; speedup 1.0000x reference)
//
#include <hip/hip_runtime.h>
#include <math.h>

#define T_LEN 1600
#define D_DIM 64
#define WIN   50
#define NPT   48          // N = WINDOW - (TAK_DIM-1)*TAK_TAU = 48
#define NPAIR 1128        // N*(N-1)/2
#define SORTN 2048
#define NBINS 20

// H1 features (beta1_med, ent1, maxp1, land1) are identically zero:
// beta1(r) = edges - N + comps is the graph cycle rank, monotone
// non-decreasing along the (sorted) radii filtration, so `ends` is never
// true. Only the H0 (MST) features and the pair-distance median matter.
__global__ __launch_bounds__(256)
void topo_feats_kernel(const float* __restrict__ latent,
                       const float* __restrict__ W,
                       const float* __restrict__ bvec,
                       float* __restrict__ out)
{
    __shared__ float s_series[WIN];
    __shared__ float s_sq[NPT];
    __shared__ float s_D[NPT][NPT];
    __shared__ float s_sort[SORTN];
    __shared__ float s_deaths[NPT - 1];
    __shared__ float s_feat[4];

    const int w   = blockIdx.x;          // 0..255 window id
    const int bb  = w >> 5;              // batch
    const int kk  = w & 31;              // window within batch
    const int tid = threadIdx.x;

    // ---- 1. series = ||latent[bb, kk*WIN + t, :]||  (8-accumulator pairwise sum)
    if (tid < WIN) {
        const float* p = latent + ((size_t)bb * T_LEN + (size_t)kk * WIN + tid) * D_DIM;
        float r[8];
#pragma unroll
        for (int q = 0; q < 8; ++q) r[q] = 0.0f;
#pragma unroll
        for (int i = 0; i < D_DIM; i += 8)
#pragma unroll
            for (int q = 0; q < 8; ++q)
                r[q] = __fadd_rn(r[q], __fmul_rn(p[i + q], p[i + q]));
        float ss = __fadd_rn(__fadd_rn(__fadd_rn(r[0], r[1]), __fadd_rn(r[2], r[3])),
                             __fadd_rn(__fadd_rn(r[4], r[5]), __fadd_rn(r[6], r[7])));
        s_series[tid] = sqrtf(ss);
    }
    __syncthreads();

    // ---- 2. Takens cloud point i = (s[i], s[i+1], s[i+2]); squared norms
    if (tid < NPT) {
        float x0 = s_series[tid], x1 = s_series[tid + 1], x2 = s_series[tid + 2];
        s_sq[tid] = __fadd_rn(__fadd_rn(__fmul_rn(x0, x0), __fmul_rn(x1, x1)),
                              __fmul_rn(x2, x2));
    }
    __syncthreads();

    // pairwise distances, float32 matching ref: sqrt(max(sq_i+sq_j-2*dot, 0))
    for (int e = tid; e < NPT * NPT; e += 256) {
        int i = e / NPT, j = e - i * NPT;
        float dot = fmaf(s_series[i + 2], s_series[j + 2],
                    fmaf(s_series[i + 1], s_series[j + 1],
                         __fmul_rn(s_series[i], s_series[j])));
        float d2 = __fsub_rn(__fadd_rn(s_sq[i], s_sq[j]), __fmul_rn(2.0f, dot));
        s_D[i][j] = sqrtf(fmaxf(d2, 0.0f));
    }
    __syncthreads();

    // ---- 3. gather i<j pair distances, bitonic sort (median only is needed)
    for (int e = tid; e < SORTN; e += 256) {
        float v = INFINITY;
        if (e < NPAIR) {
            int i = 0, rem = e;
            while (rem >= NPT - 1 - i) { rem -= NPT - 1 - i; ++i; }
            int j = i + 1 + rem;
            v = s_D[i][j];
        }
        s_sort[e] = v;
    }
    __syncthreads();

    for (int size = 2; size <= SORTN; size <<= 1) {
        for (int stride = size >> 1; stride > 0; stride >>= 1) {
            for (int idx = tid; idx < SORTN; idx += 256) {
                int p2 = idx ^ stride;
                if (p2 > idx) {
                    float a = s_sort[idx], b = s_sort[p2];
                    bool up = ((idx & size) == 0);
                    if ((a > b) == up) { s_sort[idx] = b; s_sort[p2] = a; }
                }
            }
            __syncthreads();
        }
    }

    // ---- 4. Prim MST deaths (wave 0); jnp.argmin ties -> lowest index
    if (tid < 64) {
        const int lane = tid;
        bool  intree = (lane == 0);
        float mind   = (lane < NPT) ? s_D[0][lane] : 1e30f;
        for (int it = 0; it < NPT - 1; ++it) {
            float v  = (intree || lane >= NPT) ? 1e30f : mind;
            int   id = lane;
#pragma unroll
            for (int off = 32; off > 0; off >>= 1) {
                float v2 = __shfl_xor(v, off);
                int   i2 = __shfl_xor(id, off);
                if (v2 < v || (v2 == v && i2 < id)) { v = v2; id = i2; }
            }
            if (lane == 0) s_deaths[it] = v;
            if (lane == id) intree = true;
            if (lane < NPT) mind = fminf(mind, s_D[id][lane]);
        }
    }
    __syncthreads();

    // ---- 5. H0 features (thread 0)
    if (tid == 0) {
        // vals = off-diag (each pair twice): median = avg of pair-sorted [563],[564]
        float r_med = __fadd_rn(__fmul_rn(0.5f, s_sort[563]),
                                __fmul_rn(0.5f, s_sort[564]));
        int    beta0 = 0;
        float  maxp0 = s_deaths[0];
        double ssum  = 0.0;
        for (int i = 0; i < NPT - 1; ++i) {
            float d = s_deaths[i];
            if (d > r_med) ++beta0;
            maxp0 = fmaxf(maxp0, d);
            if (d > 0.0f) ssum += (double)d;
        }
        double ent = 0.0;
        if (ssum > 0.0) {
            for (int i = 0; i < NPT - 1; ++i) {
                float d = s_deaths[i];
                if (d > 0.0f) {
                    double pp = (double)d / ssum;
                    ent -= pp * log(pp);
                }
            }
        }
        // landscape: births=0, t = linspace(0, maxp0, 20), lam = clamp(min(t, max-t))
        double t1 = (double)maxp0, acc = 0.0;
        for (int i = 0; i < NBINS; ++i) {
            double t   = t1 * (double)i / (double)(NBINS - 1);
            double lam = fmin(t, t1 - t);
            acc += fmax(lam, 0.0);
        }
        s_feat[0] = (float)beta0;          // beta0
        s_feat[1] = (float)ent;            // ent0
        s_feat[2] = maxp0;                 // maxp0
        s_feat[3] = (float)(acc / (double)NBINS); // land0
    }
    __syncthreads();

    // ---- 6. linear head: feats = [beta0,0,ent0,0,maxp0,0,land0,0]
    if (tid < 8) {
        float o = bvec[tid]
                + s_feat[0] * W[tid * 8 + 0]
                + s_feat[1] * W[tid * 8 + 2]
                + s_feat[2] * W[tid * 8 + 4]
                + s_feat[3] * W[tid * 8 + 6];
        out[w * 8 + tid] = o;
    }
}

extern "C" void kernel_launch(void* const* d_in, const int* in_sizes, int n_in,
                              void* d_out, int out_size, void* d_ws, size_t ws_size,
                              hipStream_t stream)
{
    const float* latent = (const float*)d_in[0];
    const float* W      = (const float*)d_in[1];
    const float* bvec   = (const float*)d_in[2];
    float*       out    = (float*)d_out;

    topo_feats_kernel<<<dim3(256), dim3(256), 0, stream>>>(latent, W, bvec, out);

    (void)in_sizes; (void)n_in; (void)out_size; (void)d_ws; (void)ws_size;
}

// Round 2
// 25.254 us; speedup vs baseline: 4.6602x; 4.6602x over previous
//
#include <hip/hip_runtime.h>
#include <math.h>

#define T_LEN 1600
#define D_DIM 64
#define WIN   50
#define NPT   48            // N = WINDOW - (TAK_DIM-1)*TAK_TAU
#define TGRID (NPT * NPT)   // 2304 off-diag enumeration grid
#define VPL   36            // 2304 / 64 values per lane for median wave
#define K_MED 1127          // rank (0-idx) of lower median among 2256 off-diag vals

// H1 features (beta1_med, ent1, maxp1, land1) are identically zero:
// beta1(r) = edges - N + comps is the graph cycle rank, monotone
// non-decreasing along the sorted-radii filtration, so `ends` never fires.
// Only H0 (Prim MST deaths) + the pair-distance median matter.
//
// Structure: 256 blocks (1 window/CU) x 256 threads.
//   P1: norms -> Takens cloud -> 48x48 distance matrix (all waves)
//   P2: wave 0 = Prim MST (serial 47 iters, deaths in registers)
//       wave 1 = exact median via barrier-free bitwise binary search
//       (independent -> concurrent on different SIMDs)
//   P3: wave 0 = wave-parallel feature reductions + linear head
__global__ __launch_bounds__(256)
void topo_feats_kernel(const float* __restrict__ latent,
                       const float* __restrict__ W,
                       const float* __restrict__ bvec,
                       float* __restrict__ out)
{
    __shared__ float s_series[WIN];
    __shared__ float s_sq[NPT];
    __shared__ float s_D[NPT][NPT];
    __shared__ float s_med;

    const int w   = blockIdx.x;          // window id
    const int bb  = w >> 5;              // batch
    const int kk  = w & 31;              // window within batch
    const int tid = threadIdx.x;

    // ---- P1a. series = ||latent[bb, kk*WIN + t, :]|| (8-acc pairwise sum,
    //           arithmetic identical to the round-1 passing version)
    if (tid < WIN) {
        const float* p = latent + ((size_t)bb * T_LEN + (size_t)kk * WIN + tid) * D_DIM;
        float r[8];
#pragma unroll
        for (int q = 0; q < 8; ++q) r[q] = 0.0f;
#pragma unroll
        for (int i = 0; i < D_DIM; i += 8)
#pragma unroll
            for (int q = 0; q < 8; ++q)
                r[q] = __fadd_rn(r[q], __fmul_rn(p[i + q], p[i + q]));
        float ss = __fadd_rn(__fadd_rn(__fadd_rn(r[0], r[1]), __fadd_rn(r[2], r[3])),
                             __fadd_rn(__fadd_rn(r[4], r[5]), __fadd_rn(r[6], r[7])));
        s_series[tid] = sqrtf(ss);
    }
    __syncthreads();

    // ---- P1b. Takens squared norms
    if (tid < NPT) {
        float x0 = s_series[tid], x1 = s_series[tid + 1], x2 = s_series[tid + 2];
        s_sq[tid] = __fadd_rn(__fadd_rn(__fmul_rn(x0, x0), __fmul_rn(x1, x1)),
                              __fmul_rn(x2, x2));
    }
    __syncthreads();

    // ---- P1c. pairwise distances (identical arithmetic to passing version)
    for (int e = tid; e < TGRID; e += 256) {
        int i = e / NPT, j = e - i * NPT;
        float dot = fmaf(s_series[i + 2], s_series[j + 2],
                    fmaf(s_series[i + 1], s_series[j + 1],
                         __fmul_rn(s_series[i], s_series[j])));
        float d2 = __fsub_rn(__fadd_rn(s_sq[i], s_sq[j]), __fmul_rn(2.0f, dot));
        s_D[i][j] = sqrtf(fmaxf(d2, 0.0f));
    }
    __syncthreads();

    const int wv   = tid >> 6;
    const int lane = tid & 63;
    float dreg = 0.0f;                   // lane `it` holds MST death `it`

    if (wv == 0) {
        // ---- P2a. Prim MST deaths (serial, but cheap per-iter argmin)
        bool  intree = (lane == 0);
        float mind   = (lane < NPT) ? s_D[0][lane] : 1e30f;
        for (int it = 0; it < NPT - 1; ++it) {
            float cand = (intree || lane >= NPT) ? 1e30f : mind;
            float wmin = cand;
#pragma unroll
            for (int off = 32; off > 0; off >>= 1)
                wmin = fminf(wmin, __shfl_xor(wmin, off));
            if (lane == it) dreg = wmin;
            // lowest-index argmin (== jnp.argmin; multiset also tie-invariant)
            unsigned long long m = __ballot((lane < NPT) && (cand == wmin));
            int id = __ffsll((unsigned long long)m) - 1;
            if (lane == id) intree = true;
            if (lane < NPT) mind = fminf(mind, s_D[id][lane]);
        }
    } else if (wv == 1) {
        // ---- P2b. exact median of the 2256 off-diag distances via
        //           bitwise binary search (floats >= 0 are uint-ordered).
        unsigned ub[VPL];
#pragma unroll
        for (int r = 0; r < VPL; ++r) {
            int e = lane + 64 * r;               // covers 0..2303 exactly
            int i = e / NPT, j = e - NPT * i;
            ub[r] = (i == j) ? 0xFFFFFFFFu : __float_as_uint(s_D[i][j]);
        }
        unsigned lo = 0;
        for (int bit = 30; bit >= 0; --bit) {
            unsigned probe = lo | (1u << bit);
            int c = 0;
#pragma unroll
            for (int r = 0; r < VPL; ++r) c += (ub[r] < probe) ? 1 : 0;
#pragma unroll
            for (int off = 32; off > 0; off >>= 1) c += __shfl_xor(c, off);
            if (c <= K_MED) lo = probe;          // kth-smallest bit-build
        }
        const unsigned v0 = lo;                  // rank-1127 value
        int cle = 0; unsigned mn = 0xFFFFFFFFu;
#pragma unroll
        for (int r = 0; r < VPL; ++r) {
            if (ub[r] <= v0) ++cle; else mn = (ub[r] < mn) ? ub[r] : mn;
        }
#pragma unroll
        for (int off = 32; off > 0; off >>= 1) {
            cle += __shfl_xor(cle, off);
            unsigned m2 = (unsigned)__shfl_xor((int)mn, off);
            mn = (m2 < mn) ? m2 : mn;
        }
        unsigned v1 = (cle >= K_MED + 2) ? v0 : mn;   // rank-1128 value
        if (lane == 0)
            s_med = __fadd_rn(__fmul_rn(0.5f, __uint_as_float(v0)),
                              __fmul_rn(0.5f, __uint_as_float(v1)));
    }
    __syncthreads();

    // ---- P3. wave-parallel H0 features + linear head (wave 0)
    if (wv == 0) {
        const float rmed = s_med;
        const bool  isd  = (lane < NPT - 1);
        const float d    = isd ? dreg : 0.0f;

        float beta0 = (float)__popcll(__ballot(isd && (d > rmed)));

        float mx = isd ? d : -INFINITY;
#pragma unroll
        for (int off = 32; off > 0; off >>= 1)
            mx = fmaxf(mx, __shfl_xor(mx, off));

        float sv = (isd && d > 0.0f) ? d : 0.0f;
        float ss = sv;
#pragma unroll
        for (int off = 32; off > 0; off >>= 1) ss += __shfl_xor(ss, off);

        float p    = sv / ss;                       // ss > 0 always here
        float term = (p > 0.0f) ? -p * logf(p) : 0.0f;
        float ent  = term;
#pragma unroll
        for (int off = 32; off > 0; off >>= 1) ent += __shfl_xor(ent, off);

        // landscape: births=0, t in linspace(0, mx, 20), lam = min(t, mx-t)+
        float step = mx / 19.0f;
        float t    = step * (float)lane;
        float lam  = (lane < 20) ? fmaxf(fminf(t, mx - t), 0.0f) : 0.0f;
        float land = lam;
#pragma unroll
        for (int off = 32; off > 0; off >>= 1) land += __shfl_xor(land, off);
        land *= (1.0f / 20.0f);

        // feats = [beta0, 0, ent0, 0, maxp0, 0, land0, 0] @ W.T + b
        if (lane < 8) {
            float o = bvec[lane]
                    + beta0 * W[lane * 8 + 0]
                    + ent   * W[lane * 8 + 2]
                    + mx    * W[lane * 8 + 4]
                    + land  * W[lane * 8 + 6];
            out[w * 8 + lane] = o;
        }
    }
}

extern "C" void kernel_launch(void* const* d_in, const int* in_sizes, int n_in,
                              void* d_out, int out_size, void* d_ws, size_t ws_size,
                              hipStream_t stream)
{
    const float* latent = (const float*)d_in[0];
    const float* W      = (const float*)d_in[1];
    const float* bvec   = (const float*)d_in[2];
    float*       out    = (float*)d_out;

    topo_feats_kernel<<<dim3(256), dim3(256), 0, stream>>>(latent, W, bvec, out);

    (void)in_sizes; (void)n_in; (void)out_size; (void)d_ws; (void)ws_size;
}